// Round 6
// baseline (9853.716 us; speedup 1.0000x reference)
//
#include <hip/hip_runtime.h>

using u16 = unsigned short;
using u32 = unsigned int;
using bf16x8 = __attribute__((ext_vector_type(8))) short;
using f32x4  = __attribute__((ext_vector_type(4))) float;

// ---------------- workspace layout (bytes) ----------------
static constexpr size_t XU_OFF = 0;
static constexpr size_t XU_BYTES = (size_t)512 * 64 * 4096 * 2;      // 256 MiB
static constexpr size_t XB_OFF = XU_OFF + XU_BYTES;
static constexpr size_t XB_BYTES = (size_t)64 * 512 * 1024 * 2;      // 64 MiB
static constexpr size_t UT_OFF = XB_OFF + XB_BYTES;
static constexpr size_t WT_BYTES = (size_t)4096 * 1024 * 2;          // 8 MiB
static constexpr size_t VT_OFF = UT_OFF + WT_BYTES;
static constexpr size_t BP_OFF = VT_OFF + WT_BYTES;
static constexpr size_t BP_BYTES = 4096 * 4;
// tagged h planes: [2 parity][4 group][16 row][1024 col] u32 each
static constexpr size_t HT_PLANE = (size_t)2 * 4 * 16 * 1024 * 4;    // 512 KiB
static constexpr size_t HTHI_OFF = BP_OFF + BP_BYTES;
static constexpr size_t HTLO_OFF = HTHI_OFF + HT_PLANE;

__device__ __forceinline__ float bf2f(u32 u) {
    return __uint_as_float(u << 16);
}
__device__ __forceinline__ u16 f2bf(float f) {
    u32 u = __float_as_uint(f);
    u32 r = (u + 0x7FFFu + ((u >> 16) & 1u)) >> 16;
    return (u16)r;
}

// ------------- x fp32 -> bf16 -------------
__global__ void cvt_x_kernel(const float4* __restrict__ x, uint2* __restrict__ xb) {
    int i = blockIdx.x * 256 + threadIdx.x;
#pragma unroll
    for (int k = 0; k < 8; ++k) {
        int idx = i + k * 1048576;
        float4 v = x[idx];
        uint2 o;
        o.x = (u32)f2bf(v.x) | ((u32)f2bf(v.y) << 16);
        o.y = (u32)f2bf(v.z) | ((u32)f2bf(v.w) << 16);
        xb[idx] = o;
    }
}

// ------------- repack: U/V fp32 -> bf16, K-contiguous, gate-interleaved columns -------------
__global__ void repack_kernel(const float* U0, const float* U1, const float* U2, const float* U3,
                              const float* V0, const float* V1, const float* V2, const float* V3,
                              u16* UT, u16* VT) {
    __shared__ u16 tile[64][65];
    int bx  = blockIdx.x;
    int mat = bx >> 8;
    int rem = bx & 255;
    int tf = rem >> 4, th = rem & 15;
    int f0 = tf * 64, h0 = th * 64;
    const float* srcs[8] = {U0, U1, U2, U3, V0, V1, V2, V3};
    const float* s = srcs[mat];
    u16* d = (mat < 4) ? UT : VT;
    int g = mat & 3;
    int c = threadIdx.x & 63;
    int r = threadIdx.x >> 6;
#pragma unroll
    for (int i = 0; i < 16; ++i) {
        int fr = r + i * 4;
        tile[fr][c] = f2bf(s[(size_t)(f0 + fr) * 1024 + h0 + c]);
    }
    __syncthreads();
#pragma unroll
    for (int i = 0; i < 16; ++i) {
        int hcl = r + i * 4;
        d[(size_t)((h0 + hcl) * 4 + g) * 1024 + f0 + c] = tile[c][hcl];
    }
}

// ------------- bias pack -------------
__global__ void bias_kernel(const float* b0, const float* b1, const float* b2, const float* b3,
                            float* bp) {
    int n = blockIdx.x * 256 + threadIdx.x;
    int g = n & 3, hc = n >> 2;
    const float* bs[4] = {b0, b1, b2, b3};
    bp[n] = bs[g][hc];
}

// ------------- xU GEMM -------------
__global__ void __launch_bounds__(256) gemm_xu_kernel(const u16* __restrict__ xb,
                                                      const u16* __restrict__ UT,
                                                      const float* __restrict__ bp,
                                                      u16* __restrict__ xu) {
    int bx = blockIdx.x;
    int nt = bx & 31, mt = bx >> 5;
    int tid = threadIdx.x;
    int lane = tid & 63, wv = tid >> 6;
    int wm = wv & 1, wn = wv >> 1;
    int l15 = lane & 15, quad = lane >> 4;

    int arow0 = mt * 128 + wm * 64 + l15;
    int brow0 = nt * 128 + wn * 64 + l15;

    f32x4 acc[4][4];
#pragma unroll
    for (int i = 0; i < 4; ++i)
#pragma unroll
        for (int j = 0; j < 4; ++j) acc[i][j] = f32x4{0.f, 0.f, 0.f, 0.f};

    float biasv[4];
#pragma unroll
    for (int j = 0; j < 4; ++j) biasv[j] = bp[brow0 + 16 * j];

    const u16* abase = xb + (size_t)arow0 * 1024;
    const u16* bbase = UT + (size_t)brow0 * 1024;

#pragma unroll 2
    for (int kk = 0; kk < 32; ++kk) {
        int ko = kk * 32 + quad * 8;
        bf16x8 af[4], bfv[4];
#pragma unroll
        for (int i = 0; i < 4; ++i)
            af[i] = *(const bf16x8*)(abase + (size_t)i * 16 * 1024 + ko);
#pragma unroll
        for (int j = 0; j < 4; ++j)
            bfv[j] = *(const bf16x8*)(bbase + (size_t)j * 16 * 1024 + ko);
#pragma unroll
        for (int i = 0; i < 4; ++i)
#pragma unroll
            for (int j = 0; j < 4; ++j)
                acc[i][j] = __builtin_amdgcn_mfma_f32_16x16x32_bf16(af[i], bfv[j], acc[i][j], 0, 0, 0);
    }

#pragma unroll
    for (int i = 0; i < 4; ++i) {
        int rbase = mt * 128 + wm * 64 + 16 * i + quad * 4;
#pragma unroll
        for (int j = 0; j < 4; ++j) {
            int col = brow0 + 16 * j;
            float bj = biasv[j];
#pragma unroll
            for (int rg = 0; rg < 4; ++rg) {
                int r = rbase + rg;
                int b_i = r >> 9, t_i = r & 511;
                xu[((size_t)(t_i * 64 + b_i) << 12) + col] = f2bf(acc[i][j][rg] + bj);
            }
        }
    }
}

// ------------- recurrent scan: barrier-free epoch-tagged dataflow -------------
// 256 blocks x 256 threads, 1/CU (cooperative launch for co-residency).
// Group g=bx&3 owns batch rows [16g,16g+16); block cb=bx>>2 owns packed cols
// [64cb,64cb+64). V-slice LDS-resident. h published as per-word tagged u32
// (epoch<<16 | bf16) hi+lo planes, write-through relaxed agent stores —
// NO drain, NO flags, NO barrier, NO acquire-inv. Consumers load tagged words
// with relaxed agent atomic loads and retry until tag==t. 2-deep parity
// buffering is safe: seeing any word of a block's step-s slice proves (via
// that block's internal zs __syncthreads) all its step-(s-1) reads finished,
// and advancing to s+1 requires seeing every block's slice.
// Split-K: wave wv owns kk in [8wv,8wv+8) for all 4 n-tiles; partial sums
// reduced through LDS zs[4][64][17].
__global__ void __launch_bounds__(256) lstm_rec_kernel(const u16* __restrict__ xu,
                                                       const u16* __restrict__ VT,
                                                       u32* hhi,
                                                       u32* hlo,
                                                       float* __restrict__ out) {
    constexpr int VS_STRIDE = 1032;
    __shared__ u16  Vs[64 * VS_STRIDE];          // 132,096 B
    __shared__ float zs[4][64][17];              // 17,408 B

    int bx = blockIdx.x;
    int g  = bx & 3;
    int cb = bx >> 2;
    int tid = threadIdx.x;
    int lane = tid & 63, wv = tid >> 6;
    int l15 = lane & 15, quad = lane >> 4;
    int r  = tid >> 4;                            // batch row within group (0..15)
    int hc = tid & 15;                            // h-col within block (0..15)
    int wv8 = wv * 8;

    {   // stage V-slice: packed cols [64cb, 64cb+64), K-contiguous
        const u16* src = VT + (size_t)cb * 64 * 1024;
#pragma unroll
        for (int it = 0; it < 32; ++it) {
            int id = it * 256 + tid;
            int row = id >> 7;
            int c8  = id & 127;
            *(uint4*)&Vs[row * VS_STRIDE + c8 * 8] = *(const uint4*)(src + row * 1024 + c8 * 8);
        }
    }
    __syncthreads();

    float c = 0.f;
    float h = 0.f;

    uint2 xraw = *(const uint2*)(xu + ((size_t)(g * 16 + r) << 12) + cb * 64 + hc * 4);

    for (int t = 0; t < 512; ++t) {
        f32x4 acc[4];
#pragma unroll
        for (int nt = 0; nt < 4; ++nt) acc[nt] = f32x4{0.f, 0.f, 0.f, 0.f};

        if (t) {
            const u32* hiB = hhi + (((size_t)(t & 1) * 4 + g) * 16 + l15) * 1024 + quad * 8;
            const u32* loB = hlo + (((size_t)(t & 1) * 4 + g) * 16 + l15) * 1024 + quad * 8;
            u32 we = (u32)t << 16;
            u32 whi[4][8], wlo[4][8];

#define LDH(S, KK) do {                                                          \
            const u32* _bh = hiB + (wv8 + (KK)) * 32;                            \
            const u32* _bl = loB + (wv8 + (KK)) * 32;                            \
            _Pragma("unroll")                                                    \
            for (int j = 0; j < 8; ++j)                                          \
                whi[S][j] = __hip_atomic_load(_bh + j, __ATOMIC_RELAXED,         \
                                              __HIP_MEMORY_SCOPE_AGENT);         \
            _Pragma("unroll")                                                    \
            for (int j = 0; j < 8; ++j)                                          \
                wlo[S][j] = __hip_atomic_load(_bl + j, __ATOMIC_RELAXED,         \
                                              __HIP_MEMORY_SCOPE_AGENT);         \
        } while (0)

#define CHECKH(S, KK) do {                                                       \
            for (;;) {                                                           \
                u32 bad = 0;                                                     \
                _Pragma("unroll")                                                \
                for (int j = 0; j < 8; ++j) {                                    \
                    bad |= (whi[S][j] ^ we);                                     \
                    bad |= (wlo[S][j] ^ we);                                     \
                }                                                                \
                if (!__any((bad & 0xFFFF0000u) != 0u)) break;                    \
                __builtin_amdgcn_s_sleep(1);                                     \
                LDH(S, KK);                                                      \
            }                                                                    \
        } while (0)

#define DOMFMA(S, KK) do {                                                       \
            u32 ph[4], pl[4];                                                    \
            _Pragma("unroll")                                                    \
            for (int i = 0; i < 4; ++i) {                                        \
                ph[i] = __builtin_amdgcn_perm(whi[S][2*i+1], whi[S][2*i],        \
                                              0x05040100u);                      \
                pl[i] = __builtin_amdgcn_perm(wlo[S][2*i+1], wlo[S][2*i],        \
                                              0x05040100u);                      \
            }                                                                    \
            union { u32 u[4]; bf16x8 v; } cva, cvb;                              \
            cva.u[0]=ph[0]; cva.u[1]=ph[1]; cva.u[2]=ph[2]; cva.u[3]=ph[3];      \
            cvb.u[0]=pl[0]; cvb.u[1]=pl[1]; cvb.u[2]=pl[2]; cvb.u[3]=pl[3];      \
            _Pragma("unroll")                                                    \
            for (int nt = 0; nt < 4; ++nt) {                                     \
                bf16x8 bfr = *(const bf16x8*)(Vs + (nt*16 + l15) * VS_STRIDE +   \
                                              (wv8 + (KK)) * 32 + quad * 8);     \
                acc[nt] = __builtin_amdgcn_mfma_f32_16x16x32_bf16(cva.v, bfr,    \
                                                                  acc[nt],0,0,0);\
                acc[nt] = __builtin_amdgcn_mfma_f32_16x16x32_bf16(cvb.v, bfr,    \
                                                                  acc[nt],0,0,0);\
            }                                                                    \
        } while (0)

            LDH(0, 0); LDH(1, 1); LDH(2, 2);
            LDH(3, 3); CHECKH(0, 0); DOMFMA(0, 0);
            LDH(0, 4); CHECKH(1, 1); DOMFMA(1, 1);
            LDH(1, 5); CHECKH(2, 2); DOMFMA(2, 2);
            LDH(2, 6); CHECKH(3, 3); DOMFMA(3, 3);
            LDH(3, 7); CHECKH(0, 4); DOMFMA(0, 4);
            CHECKH(1, 5); DOMFMA(1, 5);
            CHECKH(2, 6); DOMFMA(2, 6);
            CHECKH(3, 7); DOMFMA(3, 7);
#undef LDH
#undef CHECKH
#undef DOMFMA
        }

        // partial-sum handoff: C layout col=l15 (n within tile), row=quad*4+rg
#pragma unroll
        for (int nt = 0; nt < 4; ++nt)
#pragma unroll
            for (int rg = 0; rg < 4; ++rg)
                zs[wv][nt * 16 + l15][quad * 4 + rg] = acc[nt][rg];
        __syncthreads();

        float z0 = zs[0][hc*4+0][r] + zs[1][hc*4+0][r] + zs[2][hc*4+0][r] + zs[3][hc*4+0][r]
                 + bf2f(xraw.x & 0xFFFFu);
        float z1 = zs[0][hc*4+1][r] + zs[1][hc*4+1][r] + zs[2][hc*4+1][r] + zs[3][hc*4+1][r]
                 + bf2f(xraw.x >> 16);
        float z2 = zs[0][hc*4+2][r] + zs[1][hc*4+2][r] + zs[2][hc*4+2][r] + zs[3][hc*4+2][r]
                 + bf2f(xraw.y & 0xFFFFu);
        float z3 = zs[0][hc*4+3][r] + zs[1][hc*4+3][r] + zs[2][hc*4+3][r] + zs[3][hc*4+3][r]
                 + bf2f(xraw.y >> 16);

        float it_ = 1.f / (1.f + __expf(-z0));
        float ft_ = 1.f / (1.f + __expf(-z1));
        float gt_ = tanhf(z2);
        float ot_ = tanhf(z3);   // reference uses tanh for output gate
        c = ft_ * c + it_ * gt_;
        h = ot_ * tanhf(c);

        if (t == 511) break;     // final h never read back

        // publish tagged h words (epoch t+1), write-through, no drain needed
        u32 e = (u32)(t + 1) << 16;
        u32 hh = f2bf(h);
        float hl = h - bf2f(hh);
        size_t sidx = (((size_t)((t + 1) & 1) * 4 + g) * 16 + r) * 1024 + cb * 16 + hc;
        __hip_atomic_store(hhi + sidx, e | hh, __ATOMIC_RELAXED,
                           __HIP_MEMORY_SCOPE_AGENT);
        __hip_atomic_store(hlo + sidx, e | (u32)f2bf(hl), __ATOMIC_RELAXED,
                           __HIP_MEMORY_SCOPE_AGENT);

        // prefetch next xu (plain cached load — L2 survives now, no inv)
        xraw = *(const uint2*)(xu + ((size_t)((t + 1) * 64 + g * 16 + r) << 12) + cb * 64 + hc * 4);

        __syncthreads();         // protect zs reuse next iteration
    }

    out[(size_t)(g * 16 + r) * 1024 + cb * 16 + hc] = h;
}

extern "C" void kernel_launch(void* const* d_in, const int* in_sizes, int n_in,
                              void* d_out, int out_size, void* d_ws, size_t ws_size,
                              hipStream_t stream) {
    char* ws = (char*)d_ws;
    const float* x = (const float*)d_in[0];
    const float *U[4], *V[4], *b[4];
    for (int g = 0; g < 4; ++g) {
        U[g] = (const float*)d_in[1 + 3 * g];
        V[g] = (const float*)d_in[2 + 3 * g];
        b[g] = (const float*)d_in[3 + 3 * g];
    }
    u16*   xu = (u16*)(ws + XU_OFF);
    u16*   xb = (u16*)(ws + XB_OFF);
    u16*   UT = (u16*)(ws + UT_OFF);
    u16*   VT = (u16*)(ws + VT_OFF);
    float* bp = (float*)(ws + BP_OFF);
    u32*   hhi = (u32*)(ws + HTHI_OFF);
    u32*   hlo = (u32*)(ws + HTLO_OFF);
    float* out = (float*)d_out;

    // No memset needed: 0xAA-poisoned tags (0xAAAA) never equal epochs 1..512,
    // and t==0 skips all tagged loads.

    cvt_x_kernel<<<4096, 256, 0, stream>>>((const float4*)x, (uint2*)xb);
    repack_kernel<<<2048, 256, 0, stream>>>(U[0], U[1], U[2], U[3],
                                            V[0], V[1], V[2], V[3], UT, VT);
    bias_kernel<<<16, 256, 0, stream>>>(b[0], b[1], b[2], b[3], bp);
    gemm_xu_kernel<<<8192, 256, 0, stream>>>(xb, UT, bp, xu);

    void* args[] = {(void*)&xu, (void*)&VT, (void*)&hhi, (void*)&hlo, (void*)&out};
    hipLaunchCooperativeKernel((const void*)lstm_rec_kernel, dim3(256), dim3(256),
                               args, 0, stream);
}

// Round 7
// 5028.433 us; speedup vs baseline: 1.9596x; 1.9596x over previous
//
#include <hip/hip_runtime.h>

using u16 = unsigned short;
using u32 = unsigned int;
using u64 = unsigned long long;
using bf16x8 = __attribute__((ext_vector_type(8))) short;
using f32x4  = __attribute__((ext_vector_type(4))) float;

// ---------------- workspace layout (bytes) ----------------
static constexpr size_t XU_OFF = 0;
static constexpr size_t XU_BYTES = (size_t)512 * 64 * 4096 * 2;      // 256 MiB
static constexpr size_t XB_OFF = XU_OFF + XU_BYTES;
static constexpr size_t XB_BYTES = (size_t)64 * 512 * 1024 * 2;      // 64 MiB
static constexpr size_t UT_OFF = XB_OFF + XB_BYTES;
static constexpr size_t WT_BYTES = (size_t)4096 * 1024 * 2;          // 8 MiB
static constexpr size_t VT_OFF = UT_OFF + WT_BYTES;
static constexpr size_t BP_OFF = VT_OFF + WT_BYTES;
static constexpr size_t BP_BYTES = 4096 * 4;
// untagged h planes: [2 parity][4 group][16 row][1024 col] u16, hi + lo
static constexpr size_t HT_PLANE = (size_t)2 * 4 * 16 * 1024 * 2;    // 256 KiB
static constexpr size_t HHI_OFF = BP_OFF + BP_BYTES;
static constexpr size_t HLO_OFF = HHI_OFF + HT_PLANE;
static constexpr size_t FLAG_OFF = HLO_OFF + HT_PLANE;
static constexpr size_t FLAG_BYTES = 4096;                           // flags[g*64+cb]

__device__ __forceinline__ float bf2f(u32 u) {
    return __uint_as_float(u << 16);
}
__device__ __forceinline__ u16 f2bf(float f) {
    u32 u = __float_as_uint(f);
    u32 r = (u + 0x7FFFu + ((u >> 16) & 1u)) >> 16;
    return (u16)r;
}

// ------------- x fp32 -> bf16 -------------
__global__ void cvt_x_kernel(const float4* __restrict__ x, uint2* __restrict__ xb) {
    int i = blockIdx.x * 256 + threadIdx.x;
#pragma unroll
    for (int k = 0; k < 8; ++k) {
        int idx = i + k * 1048576;
        float4 v = x[idx];
        uint2 o;
        o.x = (u32)f2bf(v.x) | ((u32)f2bf(v.y) << 16);
        o.y = (u32)f2bf(v.z) | ((u32)f2bf(v.w) << 16);
        xb[idx] = o;
    }
}

// ------------- repack: U/V fp32 -> bf16, K-contiguous, gate-interleaved columns -------------
__global__ void repack_kernel(const float* U0, const float* U1, const float* U2, const float* U3,
                              const float* V0, const float* V1, const float* V2, const float* V3,
                              u16* UT, u16* VT) {
    __shared__ u16 tile[64][65];
    int bx  = blockIdx.x;
    int mat = bx >> 8;
    int rem = bx & 255;
    int tf = rem >> 4, th = rem & 15;
    int f0 = tf * 64, h0 = th * 64;
    const float* srcs[8] = {U0, U1, U2, U3, V0, V1, V2, V3};
    const float* s = srcs[mat];
    u16* d = (mat < 4) ? UT : VT;
    int g = mat & 3;
    int c = threadIdx.x & 63;
    int r = threadIdx.x >> 6;
#pragma unroll
    for (int i = 0; i < 16; ++i) {
        int fr = r + i * 4;
        tile[fr][c] = f2bf(s[(size_t)(f0 + fr) * 1024 + h0 + c]);
    }
    __syncthreads();
#pragma unroll
    for (int i = 0; i < 16; ++i) {
        int hcl = r + i * 4;
        d[(size_t)((h0 + hcl) * 4 + g) * 1024 + f0 + c] = tile[c][hcl];
    }
}

// ------------- bias pack -------------
__global__ void bias_kernel(const float* b0, const float* b1, const float* b2, const float* b3,
                            float* bp) {
    int n = blockIdx.x * 256 + threadIdx.x;
    int g = n & 3, hc = n >> 2;
    const float* bs[4] = {b0, b1, b2, b3};
    bp[n] = bs[g][hc];
}

// ------------- xU GEMM -------------
__global__ void __launch_bounds__(256) gemm_xu_kernel(const u16* __restrict__ xb,
                                                      const u16* __restrict__ UT,
                                                      const float* __restrict__ bp,
                                                      u16* __restrict__ xu) {
    int bx = blockIdx.x;
    int nt = bx & 31, mt = bx >> 5;
    int tid = threadIdx.x;
    int lane = tid & 63, wv = tid >> 6;
    int wm = wv & 1, wn = wv >> 1;
    int l15 = lane & 15, quad = lane >> 4;

    int arow0 = mt * 128 + wm * 64 + l15;
    int brow0 = nt * 128 + wn * 64 + l15;

    f32x4 acc[4][4];
#pragma unroll
    for (int i = 0; i < 4; ++i)
#pragma unroll
        for (int j = 0; j < 4; ++j) acc[i][j] = f32x4{0.f, 0.f, 0.f, 0.f};

    float biasv[4];
#pragma unroll
    for (int j = 0; j < 4; ++j) biasv[j] = bp[brow0 + 16 * j];

    const u16* abase = xb + (size_t)arow0 * 1024;
    const u16* bbase = UT + (size_t)brow0 * 1024;

#pragma unroll 2
    for (int kk = 0; kk < 32; ++kk) {
        int ko = kk * 32 + quad * 8;
        bf16x8 af[4], bfv[4];
#pragma unroll
        for (int i = 0; i < 4; ++i)
            af[i] = *(const bf16x8*)(abase + (size_t)i * 16 * 1024 + ko);
#pragma unroll
        for (int j = 0; j < 4; ++j)
            bfv[j] = *(const bf16x8*)(bbase + (size_t)j * 16 * 1024 + ko);
#pragma unroll
        for (int i = 0; i < 4; ++i)
#pragma unroll
            for (int j = 0; j < 4; ++j)
                acc[i][j] = __builtin_amdgcn_mfma_f32_16x16x32_bf16(af[i], bfv[j], acc[i][j], 0, 0, 0);
    }

#pragma unroll
    for (int i = 0; i < 4; ++i) {
        int rbase = mt * 128 + wm * 64 + 16 * i + quad * 4;
#pragma unroll
        for (int j = 0; j < 4; ++j) {
            int col = brow0 + 16 * j;
            float bj = biasv[j];
#pragma unroll
            for (int rg = 0; rg < 4; ++rg) {
                int r = rbase + rg;
                int b_i = r >> 9, t_i = r & 511;
                xu[((size_t)(t_i * 64 + b_i) << 12) + col] = f2bf(acc[i][j][rg] + bj);
            }
        }
    }
}

// ------------- recurrent scan: flags + uncached u64 h loads, split-K, no inv -------------
// 256 blocks x 256 threads, 1/CU. Group g=bx&3 owns batch rows [16g,16g+16);
// block cb=bx>>2 owns packed cols [64cb,64cb+64). V-slice in LDS.
// Per step: wave wv polls flags of its 16 producers [16wv,16wv+16) (kk-chunks
// [8wv,8wv+8) cover exactly their columns), then streams untagged h hi/lo via
// relaxed agent-scope u64 atomic loads (cache-bypassing -> always fresh; NO
// buffer_inv, so xu/V cache state survives). Split-K partials reduced via
// LDS zs[4][64][17]. Publish: write-through u16 stores + vmcnt drain +
// block flag store. Parity-slot safety: block publishes h_{t+2} (overwriting
// h_t) only after all 4 waves saw flags>=t+1 from all 64 blocks (union of
// wave subsets), proving every block finished reading h_t.
__global__ void __launch_bounds__(256) lstm_rec_kernel(const u16* __restrict__ xu,
                                                       const u16* __restrict__ VT,
                                                       u16* hhi,
                                                       u16* hlo,
                                                       u32* flags,
                                                       float* __restrict__ out) {
    constexpr int VS_STRIDE = 1032;
    __shared__ u16  Vs[64 * VS_STRIDE];          // 132,096 B
    __shared__ float zs[4][64][17];              // 17,408 B

    int bx = blockIdx.x;
    int g  = bx & 3;
    int cb = bx >> 2;
    int tid = threadIdx.x;
    int lane = tid & 63, wv = tid >> 6;
    int l15 = lane & 15, quad = lane >> 4;
    int r  = tid >> 4;                            // batch row within group
    int hc = tid & 15;                            // h-col within block
    int wv8 = wv * 8;

    {   // stage V-slice: packed cols [64cb, 64cb+64), K-contiguous
        const u16* src = VT + (size_t)cb * 64 * 1024;
#pragma unroll
        for (int it = 0; it < 32; ++it) {
            int id = it * 256 + tid;
            int row = id >> 7;
            int c8  = id & 127;
            *(uint4*)&Vs[row * VS_STRIDE + c8 * 8] = *(const uint4*)(src + row * 1024 + c8 * 8);
        }
    }
    __syncthreads();

    u32* gflags = flags + g * 64;
    int myp = 16 * wv + l15;                      // producer polled by this lane

    float c = 0.f;
    float h = 0.f;

    uint2 xraw = *(const uint2*)(xu + ((size_t)(g * 16 + r) << 12) + cb * 64 + hc * 4);

    for (int t = 0; t < 512; ++t) {
        f32x4 acc[4];
#pragma unroll
        for (int nt = 0; nt < 4; ++nt) acc[nt] = f32x4{0.f, 0.f, 0.f, 0.f};

        if (t) {
            // 1) poll this wave's 16 producers (lanes replicate x4; ballot all-set)
            for (;;) {
                u32 f = __hip_atomic_load(gflags + myp, __ATOMIC_RELAXED,
                                          __HIP_MEMORY_SCOPE_AGENT);
                if (__ballot(f >= (u32)t) == ~0ull) break;
                __builtin_amdgcn_s_sleep(1);
            }
            asm volatile("" ::: "memory");        // keep h loads below the poll

            // 2) stream h fragments (untagged, uncached-coherent u64 loads)
            const u16* hiB = hhi + (((size_t)(t & 1) * 4 + g) * 16 + l15) * 1024;
            const u16* loB = hlo + (((size_t)(t & 1) * 4 + g) * 16 + l15) * 1024;
            u64 vh[8][2], vl[8][2];
#pragma unroll
            for (int j = 0; j < 8; ++j) {
                u64* ph = (u64*)(hiB + (wv8 + j) * 32 + quad * 8);
                u64* pl = (u64*)(loB + (wv8 + j) * 32 + quad * 8);
                vh[j][0] = __hip_atomic_load(ph,     __ATOMIC_RELAXED, __HIP_MEMORY_SCOPE_AGENT);
                vh[j][1] = __hip_atomic_load(ph + 1, __ATOMIC_RELAXED, __HIP_MEMORY_SCOPE_AGENT);
                vl[j][0] = __hip_atomic_load(pl,     __ATOMIC_RELAXED, __HIP_MEMORY_SCOPE_AGENT);
                vl[j][1] = __hip_atomic_load(pl + 1, __ATOMIC_RELAXED, __HIP_MEMORY_SCOPE_AGENT);
            }
#pragma unroll
            for (int j = 0; j < 8; ++j) {
                union { u64 q[2]; bf16x8 v; } ah, al;
                ah.q[0] = vh[j][0]; ah.q[1] = vh[j][1];
                al.q[0] = vl[j][0]; al.q[1] = vl[j][1];
#pragma unroll
                for (int nt = 0; nt < 4; ++nt) {
                    bf16x8 bfr = *(const bf16x8*)(Vs + (nt * 16 + l15) * VS_STRIDE +
                                                  (wv8 + j) * 32 + quad * 8);
                    acc[nt] = __builtin_amdgcn_mfma_f32_16x16x32_bf16(ah.v, bfr, acc[nt], 0, 0, 0);
                    acc[nt] = __builtin_amdgcn_mfma_f32_16x16x32_bf16(al.v, bfr, acc[nt], 0, 0, 0);
                }
            }
        }

        // 3) split-K partial handoff: C layout col=l15, row=quad*4+rg
#pragma unroll
        for (int nt = 0; nt < 4; ++nt)
#pragma unroll
            for (int rg = 0; rg < 4; ++rg)
                zs[wv][nt * 16 + l15][quad * 4 + rg] = acc[nt][rg];
        __syncthreads();

        float z0 = zs[0][hc*4+0][r] + zs[1][hc*4+0][r] + zs[2][hc*4+0][r] + zs[3][hc*4+0][r]
                 + bf2f(xraw.x & 0xFFFFu);
        float z1 = zs[0][hc*4+1][r] + zs[1][hc*4+1][r] + zs[2][hc*4+1][r] + zs[3][hc*4+1][r]
                 + bf2f(xraw.x >> 16);
        float z2 = zs[0][hc*4+2][r] + zs[1][hc*4+2][r] + zs[2][hc*4+2][r] + zs[3][hc*4+2][r]
                 + bf2f(xraw.y & 0xFFFFu);
        float z3 = zs[0][hc*4+3][r] + zs[1][hc*4+3][r] + zs[2][hc*4+3][r] + zs[3][hc*4+3][r]
                 + bf2f(xraw.y >> 16);

        float it_ = 1.f / (1.f + __expf(-z0));
        float ft_ = 1.f / (1.f + __expf(-z1));
        float gt_ = tanhf(z2);
        float ot_ = tanhf(z3);   // reference uses tanh for output gate
        c = ft_ * c + it_ * gt_;
        h = ot_ * tanhf(c);

        if (t == 511) break;     // final h never read back

        // 4) prefetch next xu (cached; caches are never invalidated now)
        xraw = *(const uint2*)(xu + ((size_t)((t + 1) * 64 + g * 16 + r) << 12) + cb * 64 + hc * 4);

        // 5) publish h (write-through) + drain + block flag
        u32 hh = f2bf(h);
        float hl = h - bf2f(hh);
        size_t sidx = (((size_t)((t + 1) & 1) * 4 + g) * 16 + r) * 1024 + cb * 16 + hc;
        __hip_atomic_store(hhi + sidx, (u16)hh, __ATOMIC_RELAXED,
                           __HIP_MEMORY_SCOPE_AGENT);
        __hip_atomic_store(hlo + sidx, f2bf(hl), __ATOMIC_RELAXED,
                           __HIP_MEMORY_SCOPE_AGENT);
        asm volatile("s_waitcnt vmcnt(0)" ::: "memory");
        __syncthreads();          // also protects zs reuse next iteration
        if (tid == 0)
            __hip_atomic_store(gflags + cb, (u32)(t + 1), __ATOMIC_RELAXED,
                               __HIP_MEMORY_SCOPE_AGENT);
    }

    out[(size_t)(g * 16 + r) * 1024 + cb * 16 + hc] = h;
}

extern "C" void kernel_launch(void* const* d_in, const int* in_sizes, int n_in,
                              void* d_out, int out_size, void* d_ws, size_t ws_size,
                              hipStream_t stream) {
    char* ws = (char*)d_ws;
    const float* x = (const float*)d_in[0];
    const float *U[4], *V[4], *b[4];
    for (int g = 0; g < 4; ++g) {
        U[g] = (const float*)d_in[1 + 3 * g];
        V[g] = (const float*)d_in[2 + 3 * g];
        b[g] = (const float*)d_in[3 + 3 * g];
    }
    u16*   xu = (u16*)(ws + XU_OFF);
    u16*   xb = (u16*)(ws + XB_OFF);
    u16*   UT = (u16*)(ws + UT_OFF);
    u16*   VT = (u16*)(ws + VT_OFF);
    float* bp = (float*)(ws + BP_OFF);
    u16*   hhi = (u16*)(ws + HHI_OFF);
    u16*   hlo = (u16*)(ws + HLO_OFF);
    u32*   flags = (u32*)(ws + FLAG_OFF);
    float* out = (float*)d_out;

    // flags must start at 0 (0xAA poison would satisfy any poll immediately)
    hipMemsetAsync(ws + FLAG_OFF, 0, FLAG_BYTES, stream);

    cvt_x_kernel<<<4096, 256, 0, stream>>>((const float4*)x, (uint2*)xb);
    repack_kernel<<<2048, 256, 0, stream>>>(U[0], U[1], U[2], U[3],
                                            V[0], V[1], V[2], V[3], UT, VT);
    bias_kernel<<<16, 256, 0, stream>>>(b[0], b[1], b[2], b[3], bp);
    gemm_xu_kernel<<<8192, 256, 0, stream>>>(xb, UT, bp, xu);

    void* args[] = {(void*)&xu, (void*)&VT, (void*)&hhi, (void*)&hlo,
                    (void*)&flags, (void*)&out};
    hipLaunchCooperativeKernel((const void*)lstm_rec_kernel, dim3(256), dim3(256),
                               args, 0, stream);
}